// Round 10
// baseline (185.830 us; speedup 1.0000x reference)
//
#include <hip/hip_runtime.h>
#include <cstdint>

#define NB 2
#define NSEQ 2048
#define CDIM 768
#define NH 12
#define HD 64
#define NTOK (NB*NSEQ)        // 4096
#define QKV_COLS (3*CDIM)     // 2304
#define NBLK_ATTN (((NSEQ/64)*NH*NB)*2)  // 1536: split-K2
#define NBLK_RED  ((NSEQ/64)*NH*NB)      // 768

typedef short bf16x8 __attribute__((ext_vector_type(8)));
typedef short bf16x4 __attribute__((ext_vector_type(4)));
typedef float f32x4  __attribute__((ext_vector_type(4)));
typedef short short4v __attribute__((ext_vector_type(4)));
typedef unsigned int uint2v __attribute__((ext_vector_type(2)));
typedef unsigned int uint4v __attribute__((ext_vector_type(4)));

#define MFMA16(a,b,c) __builtin_amdgcn_mfma_f32_16x16x32_bf16(a,b,c,0,0,0)

__device__ __forceinline__ short f2b(float f) {
    uint32_t u = __builtin_bit_cast(uint32_t, f);
    u += 0x7fffu + ((u >> 16) & 1u);
    return (short)(u >> 16);
}
__device__ __forceinline__ unsigned pack2(float a, float b) {
    unsigned ua = __builtin_bit_cast(unsigned, a) + 0x7fffu;
    unsigned ub = __builtin_bit_cast(unsigned, b) + 0x7fffu;
    return __builtin_amdgcn_perm(ub, ua, 0x07060302u);
}
__device__ __forceinline__ void gll16(const short* g, short* l) {
    __builtin_amdgcn_global_load_lds(
        (const __attribute__((address_space(1))) unsigned int*)g,
        (__attribute__((address_space(3))) unsigned int*)l, 16, 0, 0);
}

// ---------------------------------------------------------------------------
// Merged prep: x fp32->bf16 (blocks 0..3071), w_qkv T (..4799), w_proj T (..5375)
// ---------------------------------------------------------------------------
__global__ __launch_bounds__(256) void prep_kernel(
    const float* __restrict__ x, const float* __restrict__ w_qkv,
    const float* __restrict__ w_proj,
    short* __restrict__ xb, short* __restrict__ wqt, short* __restrict__ wpt)
{
    __shared__ float tile[32][33];
    const int bid = blockIdx.x, t = threadIdx.x;
    if (bid < 3072) {
        int i = bid * 256 + t;
        float4 v = ((const float4*)x)[i];
        short4v o = { f2b(v.x), f2b(v.y), f2b(v.z), f2b(v.w) };
        ((short4v*)xb)[i] = o;
        return;
    }
    const float* w; short* wt; int K, NC, n0, k0;
    if (bid < 3072 + 1728) {
        int r = bid - 3072;
        w = w_qkv; wt = wqt; K = CDIM; NC = QKV_COLS;
        n0 = (r % 72) * 32; k0 = (r / 72) * 32;
    } else {
        int r = bid - 4800;
        w = w_proj; wt = wpt; K = CDIM; NC = CDIM;
        n0 = (r % 24) * 32; k0 = (r / 24) * 32;
    }
    #pragma unroll
    for (int i = 0; i < 4; ++i) {
        int idx = t + i * 256; int r = idx >> 5, c = idx & 31;
        tile[r][c] = w[(size_t)(k0 + r) * NC + n0 + c];
    }
    __syncthreads();
    #pragma unroll
    for (int i = 0; i < 4; ++i) {
        int idx = t + i * 256; int r = idx >> 5, c = idx & 31;
        wt[(size_t)(n0 + r) * K + k0 + c] = f2b(tile[c][r]);
    }
}

// ---------------------------------------------------------------------------
// Shared GEMM K-loop: double-buffered BK=32, ONE barrier per stage.
// ---------------------------------------------------------------------------
#define STAGEG(K0, B) do {                                                       \
    short* a_ = As + (B)*4096; short* b_ = Bs + (B)*4096;                        \
    gll16(ag0 + (K0), a_ + wid*512);                                             \
    gll16(ag1 + (K0), a_ + 2048 + wid*512);                                      \
    gll16(bg0 + (K0), b_ + wid*512);                                             \
    gll16(bg1 + (K0), b_ + 2048 + wid*512);                                      \
} while (0)

#define COMPUTEG(B) do {                                                         \
    const short* A_ = As + (B)*4096; const short* B_ = Bs + (B)*4096;            \
    bf16x8 af_[4], bf_[4];                                                       \
    _Pragma("unroll")                                                            \
    for (int i = 0; i < 4; ++i)                                                  \
        af_[i] = *(const bf16x8*)&A_[(wA*64 + i*16 + l16) * 32 + quad*8];        \
    _Pragma("unroll")                                                            \
    for (int j = 0; j < 4; ++j)                                                  \
        bf_[j] = *(const bf16x8*)&B_[(wB*64 + j*16 + l16) * 32 + quad*8];        \
    _Pragma("unroll")                                                            \
    for (int i = 0; i < 4; ++i)                                                  \
        _Pragma("unroll")                                                        \
        for (int j = 0; j < 4; ++j)                                              \
            acc[i][j] = MFMA16(af_[i], bf_[j], acc[i][j]);                       \
} while (0)

#define GEMM_LOOP() do {                                                         \
    STAGEG(0, 0); __syncthreads();                                               \
    for (int k0 = 0; k0 < CDIM; k0 += 64) {                                      \
        STAGEG(k0 + 32, 1);                                                      \
        COMPUTEG(0);                                                             \
        __syncthreads();                                                         \
        STAGEG((k0 + 64 < CDIM) ? k0 + 64 : 0, 0);                               \
        COMPUTEG(1);                                                             \
        __syncthreads();                                                         \
    }                                                                            \
} while (0)

// ---------------------------------------------------------------------------
// GEMM1: qkv. Epilogue staged through LDS so ALL global stores are 128-B
// contiguous runs. q pre-scaled by 0.125. CT stride 136 shorts (16B-aligned).
// ---------------------------------------------------------------------------
__global__ __launch_bounds__(256) void gemm_qkv(
    const short* __restrict__ A /*wqt[2304][768]*/,
    const short* __restrict__ B /*xb [4096][768]*/,
    short* __restrict__ qb, short* __restrict__ kb, short* __restrict__ vt)
{
    __shared__ __align__(16) short SM[17408];   // loop: As|Bs (32KB); epi: CT
    short* const As = SM;
    short* const Bs = SM + 8192;
    const int t = threadIdx.x;
    const int lane = t & 63, wid = t >> 6;
    const int quad = lane >> 4, l16 = lane & 15;
    const int wA = wid >> 1, wB = wid & 1;
    const int n0 = blockIdx.x * 128;
    const int m0 = blockIdx.y * 128;

    const int srow = wid * 16 + (lane >> 2), schunk = (lane & 3) * 8;
    const short* ag0 = A + (size_t)(n0 + srow) * CDIM + schunk;
    const short* ag1 = ag0 + (size_t)64 * CDIM;
    const short* bg0 = B + (size_t)(m0 + srow) * CDIM + schunk;
    const short* bg1 = bg0 + (size_t)64 * CDIM;

    f32x4 acc[4][4] = {};
    GEMM_LOOP();
    // loop ends with __syncthreads(): SM free to reuse

    const int s  = n0 / CDIM;                    // block-uniform (128 | 768)
    const int h0 = (n0 - s * CDIM) >> 6;
    const int b  = m0 >> 11;
    const float qsc = (s == 0) ? 0.125f : 1.0f;
    short* const CT = SM;

    if (s < 2) {
        // CT[tok][qkvcol]: lane writes 4 consecutive cols (packed 8B)
        #pragma unroll
        for (int i = 0; i < 4; ++i)
            #pragma unroll
            for (int j = 0; j < 4; ++j) {
                int tok = wB*64 + j*16 + l16;
                int col = wA*64 + i*16 + quad*4;
                short4v o = { f2b(acc[i][j][0]*qsc), f2b(acc[i][j][1]*qsc),
                              f2b(acc[i][j][2]*qsc), f2b(acc[i][j][3]*qsc) };
                *(short4v*)&CT[tok*136 + col] = o;
            }
        __syncthreads();
        const int tok = t >> 1, hf = t & 1;
        short* dst = (s == 0 ? qb : kb)
                   + ((size_t)(b*NH + h0 + hf) * NSEQ + (m0 & 2047) + tok) * HD;
        const short* src = &CT[tok*136 + hf*64];
        #pragma unroll
        for (int k = 0; k < 8; ++k)
            *(float4*)(dst + k*8) = *(const float4*)(src + k*8);
    } else {
        // CT[qkvcol(d)][tok]: scalar writes, then 128B-contiguous token runs
        #pragma unroll
        for (int i = 0; i < 4; ++i)
            #pragma unroll
            for (int j = 0; j < 4; ++j) {
                int tok = wB*64 + j*16 + l16;
                int col = wA*64 + i*16 + quad*4;
                #pragma unroll
                for (int r = 0; r < 4; ++r)
                    CT[(col + r)*136 + tok] = f2b(acc[i][j][r]);
            }
        __syncthreads();
        const int row = t >> 1, hf = t & 1;      // row = 2 heads x 64 d
        const int hh = h0 + (row >> 6), d = row & 63;
        short* dst = vt + ((size_t)(b*NH + hh) * HD + d) * NSEQ
                   + (m0 & 2047) + hf*64;
        const short* src = &CT[row*136 + hf*64];
        #pragma unroll
        for (int k = 0; k < 8; ++k)
            *(float4*)(dst + k*8) = *(const float4*)(src + k*8);
    }
}

// ---------------------------------------------------------------------------
// Flash attention v10 = v9 + split-K2. Block = (64q, bh, split of 1024 keys).
// Writes UNNORMALIZED fp32 O-partial [q][d] + l-partial to workspace.
// ---------------------------------------------------------------------------
#define STAGE64(KT, BUF) do {                                                    \
    short* kd_ = (BUF);                                                          \
    short* vd_ = (BUF) + 4096;                                                   \
    _Pragma("unroll")                                                            \
    for (int j = 0; j < 2; ++j) {                                                \
        gll16(kp + (size_t)((KT) + sRow[j]) * HD + sC[j]*8, kd_ + wid*1024 + j*512); \
        gll16(vp + (size_t)sRow[j] * NSEQ + (KT) + sC[j]*8, vd_ + wid*1024 + j*512); \
    }                                                                            \
} while (0)

#define BODY_S(KT, BUF, pP, vL) do {                                             \
    const short* Kb_ = (BUF);                                                    \
    const short* Vb_ = (BUF) + 4096;                                             \
    int4 mi_ = *(const int4*)(mp + (KT) + kbase);                                \
    bf16x8 kf0_ = *(const bf16x8*)&Kb_[krow64 + kc0];                            \
    bf16x8 kf1_ = *(const bf16x8*)&Kb_[krow64 + kc1];                            \
    f32x4 s_[4] = {};                                                            \
    _Pragma("unroll")                                                            \
    for (int jt = 0; jt < 4; ++jt) {                                             \
        s_[jt] = MFMA16(kf0_, qf[jt][0], s_[jt]);                                \
        s_[jt] = MFMA16(kf1_, qf[jt][1], s_[jt]);                                \
    }                                                                            \
    float4 m_ = {(float)mi_.x, (float)mi_.y, (float)mi_.z, (float)mi_.w};        \
    _Pragma("unroll")                                                            \
    for (int jt = 0; jt < 4; ++jt) {                                             \
        float e0 = __expf(s_[jt][0]) * m_.x;                                     \
        float e1 = __expf(s_[jt][1]) * m_.y;                                     \
        float e2 = __expf(s_[jt][2]) * m_.z;                                     \
        float e3 = __expf(s_[jt][3]) * m_.w;                                     \
        l[jt] += (e0 + e1) + (e2 + e3);                                          \
        pP[jt] = (uint2v){ pack2(e0, e1), pack2(e2, e3) };                       \
    }                                                                            \
    _Pragma("unroll")                                                            \
    for (int it = 0; it < 4; ++it)                                               \
        vL[it] = *(const bf16x4*)&Vb_[(it*16 + l16)*64 + vslot + vsub];          \
} while (0)

#define BODY_PV(pLo, vLo, pHi, vHi) do {                                         \
    bf16x8 pb_[4];                                                               \
    _Pragma("unroll")                                                            \
    for (int jt = 0; jt < 4; ++jt) {                                             \
        uint4v u_ = { pLo[jt].x, pLo[jt].y, pHi[jt].x, pHi[jt].y };              \
        pb_[jt] = __builtin_bit_cast(bf16x8, u_);                                \
    }                                                                            \
    _Pragma("unroll")                                                            \
    for (int it = 0; it < 4; ++it) {                                             \
        bf16x8 vf_ = __builtin_shufflevector(vLo[it], vHi[it], 0,1,2,3,4,5,6,7); \
        _Pragma("unroll")                                                        \
        for (int jt = 0; jt < 4; ++jt)                                           \
            o_acc[it][jt] = MFMA16(vf_, pb_[jt], o_acc[it][jt]);                 \
    }                                                                            \
} while (0)

__global__ __launch_bounds__(256) void attn_kernel(
    const short* __restrict__ qb, const short* __restrict__ kb,
    const short* __restrict__ vt, const int* __restrict__ mask,
    float* __restrict__ opart, float* __restrict__ lpart)
{
    __shared__ __align__(16) short KV2[2][8192];   // [buf][K 8KB | V 8KB]
    float (*Ob)[68] = (float(*)[68])KV2;           // epilogue alias
    float (*lsum)[64] = (float(*)[64])((char*)KV2 + 17408);

    const int t = threadIdx.x;
    const int lane = t & 63, wid = t >> 6;
    const int quad = lane >> 4, l16 = lane & 15;
    // XCD swizzle: XCD = id%8 owns 3 bh groups; idx also encodes q-tile+split
    const int id = blockIdx.x;
    const int idx = id >> 3;                 // 0..191
    const int bh = (id & 7) + ((idx % 3) << 3);
    const int rem = idx / 3;                 // 0..63
    const int q0 = (rem >> 1) << 6;
    const int split = rem & 1;
    const int koff = split << 10;            // 0 or 1024
    const int b = bh / NH, h = bh - b * NH;
    const size_t hoff = (size_t)bh * NSEQ * HD;
    const short* qp = qb + hoff;     // [N][64]  (q pre-scaled by 0.125)
    const short* kp = kb + hoff;     // [N][64]
    const short* vp = vt + hoff;     // [64][N]
    const int* mp = mask + b * NSEQ;
    const int kbase = wid * 16 + quad * 4;
    const int slab = ((bh * 32 + (q0 >> 6)) << 1) + split;

    int sRow[2], sC[2];
    #pragma unroll
    for (int j = 0; j < 2; ++j) {
        sRow[j] = wid * 16 + j * 8 + (lane >> 3);
        sC[j]   = (lane & 7) ^ (sRow[j] & 7);
    }
    const int r7 = l16 & 7;
    const int krow64 = (wid * 16 + l16) * 64;
    const int kc0 = ((quad       ^ r7) << 3);
    const int kc1 = (((quad + 4) ^ r7) << 3);
    const int vslot = (((wid*2 + (quad >> 1)) ^ r7) << 3);
    const int vsub  = (quad & 1) * 4;

    bf16x8 qf[4][2];
    #pragma unroll
    for (int jt = 0; jt < 4; ++jt) {
        const short* qr = qp + (size_t)(q0 + jt*16 + l16) * HD + quad*8;
        qf[jt][0] = *(const bf16x8*)qr;
        qf[jt][1] = *(const bf16x8*)(qr + 32);
    }

    f32x4 o_acc[4][4] = {};
    float l[4] = {0.f, 0.f, 0.f, 0.f};
    uint2v pLo[4], pHi[4];
    bf16x4 vLo[4], vHi[4];

    STAGE64(koff, KV2[0]);
    __syncthreads();

    for (int kt = koff; kt < koff + 1024; kt += 128) {
        STAGE64(kt + 64, KV2[1]);
        BODY_S(kt, KV2[0], pLo, vLo);
        __syncthreads();
        STAGE64((kt + 128 < koff + 1024) ? kt + 128 : koff, KV2[0]);
        BODY_S(kt + 64, KV2[1], pHi, vHi);
        BODY_PV(pLo, vLo, pHi, vHi);
        __syncthreads();
    }

    // ---- epilogue: cross-wave reduce in LDS, then fp32 partials out ----
    #pragma unroll
    for (int jt = 0; jt < 4; ++jt) {
        l[jt] += __shfl_xor(l[jt], 16);
        l[jt] += __shfl_xor(l[jt], 32);
        if (quad == 0) lsum[wid][jt*16 + l16] = l[jt];
    }
    for (int w = 0; w < 4; ++w) {
        __syncthreads();
        if (wid == w) {
            #pragma unroll
            for (int it = 0; it < 4; ++it)
                #pragma unroll
                for (int jt = 0; jt < 4; ++jt)
                    #pragma unroll
                    for (int r = 0; r < 4; ++r) {
                        if (w == 0)
                            Ob[it*16 + quad*4 + r][jt*16 + l16] = o_acc[it][jt][r];
                        else
                            Ob[it*16 + quad*4 + r][jt*16 + l16] += o_acc[it][jt][r];
                    }
        }
    }
    __syncthreads();

    {
        const int ql = t >> 2, dc = (t & 3) * 16;
        float* po = opart + (size_t)slab * 4096 + ql * 64 + dc;
        #pragma unroll
        for (int k = 0; k < 4; ++k) {
            float4 o4 = { Ob[dc + k*4 + 0][ql], Ob[dc + k*4 + 1][ql],
                          Ob[dc + k*4 + 2][ql], Ob[dc + k*4 + 3][ql] };
            *(float4*)(po + k*4) = o4;
        }
        if (t < 64)
            lpart[(size_t)slab * 64 + t] =
                ((lsum[0][t] + lsum[1][t]) + (lsum[2][t] + lsum[3][t]));
    }
}

// ---------------------------------------------------------------------------
// Split-K reduce: O = (O0+O1)/(l0+l1), bf16 to ao. XCD-matched to attn.
// ---------------------------------------------------------------------------
__global__ __launch_bounds__(256) void attn_reduce(
    const float* __restrict__ opart, const float* __restrict__ lpart,
    short* __restrict__ ao)
{
    const int id = blockIdx.x, t = threadIdx.x;
    const int xcd = id & 7, g = id >> 3;         // g 0..95
    const int qt = g & 31, bhhi = g >> 5;
    const int bh = xcd + (bhhi << 3);
    const int b = bh / NH, h = bh - b * NH;
    const int slab0 = (bh * 32 + qt) << 1;
    const int ql = t >> 2, dc = (t & 3) << 4;
    const float* p0 = opart + (size_t)slab0 * 4096 + ql * 64 + dc;
    const float* p1 = p0 + 4096;
    const float inv = 1.0f /
        (lpart[(size_t)slab0 * 64 + ql] + lpart[(size_t)(slab0 + 1) * 64 + ql]);
    bf16x8 oa, ob;
    #pragma unroll
    for (int k = 0; k < 2; ++k) {
        float4 a0 = ((const float4*)p0)[k*2],     a1 = ((const float4*)p0)[k*2+1];
        float4 c0 = ((const float4*)p1)[k*2],     c1 = ((const float4*)p1)[k*2+1];
        bf16x8 o8;
        o8[0] = f2b((a0.x + c0.x) * inv); o8[1] = f2b((a0.y + c0.y) * inv);
        o8[2] = f2b((a0.z + c0.z) * inv); o8[3] = f2b((a0.w + c0.w) * inv);
        o8[4] = f2b((a1.x + c1.x) * inv); o8[5] = f2b((a1.y + c1.y) * inv);
        o8[6] = f2b((a1.z + c1.z) * inv); o8[7] = f2b((a1.w + c1.w) * inv);
        if (k == 0) oa = o8; else ob = o8;
    }
    short* dst = ao + ((size_t)(b * NSEQ + qt * 64 + ql)) * CDIM + h * HD + dc;
    *(bf16x8*)dst = oa;
    *(bf16x8*)(dst + 8) = ob;
}

// ---------------------------------------------------------------------------
// GEMM2: out = ao @ w_proj + bias (fp32), dbuf K-loop.
// ---------------------------------------------------------------------------
__global__ __launch_bounds__(256) void gemm_proj(
    const short* __restrict__ A /*wpt[768][768]*/,
    const short* __restrict__ B /*ao [4096][768]*/,
    const float* __restrict__ bias, float* __restrict__ out)
{
    __shared__ short SMp[16384];
    short* const As = SMp;
    short* const Bs = SMp + 8192;
    const int t = threadIdx.x;
    const int lane = t & 63, wid = t >> 6;
    const int quad = lane >> 4, l16 = lane & 15;
    const int wA = wid >> 1, wB = wid & 1;
    const int n0 = blockIdx.x * 128;
    const int m0 = blockIdx.y * 128;

    const int srow = wid * 16 + (lane >> 2), schunk = (lane & 3) * 8;
    const short* ag0 = A + (size_t)(n0 + srow) * CDIM + schunk;
    const short* ag1 = ag0 + (size_t)64 * CDIM;
    const short* bg0 = B + (size_t)(m0 + srow) * CDIM + schunk;
    const short* bg1 = bg0 + (size_t)64 * CDIM;

    f32x4 acc[4][4] = {};
    GEMM_LOOP();

    #pragma unroll
    for (int i = 0; i < 4; ++i) {
        int col0 = n0 + wA*64 + i*16 + quad*4;
        float4 bias4 = *(const float4*)&bias[col0];
        #pragma unroll
        for (int j = 0; j < 4; ++j) {
            int tok = m0 + wB*64 + j*16 + l16;
            float4 o = { acc[i][j][0] + bias4.x, acc[i][j][1] + bias4.y,
                         acc[i][j][2] + bias4.z, acc[i][j][3] + bias4.w };
            *(float4*)(out + (size_t)tok * CDIM + col0) = o;
        }
    }
}

extern "C" void kernel_launch(void* const* d_in, const int* in_sizes, int n_in,
                              void* d_out, int out_size, void* d_ws, size_t ws_size,
                              hipStream_t stream)
{
    const float* x      = (const float*)d_in[0];
    const int*   mask   = (const int*)d_in[1];
    const float* w_qkv  = (const float*)d_in[2];
    const float* w_proj = (const float*)d_in[3];
    const float* b_proj = (const float*)d_in[4];
    float* out = (float*)d_out;

    const size_t SZ = (size_t)NTOK * CDIM;       // 3,145,728
    short* xb  = (short*)d_ws;                   // [4096][768]
    short* wqt = xb  + SZ;                       // [2304][768]
    short* wpt = wqt + (size_t)QKV_COLS * CDIM;  // [768][768]
    short* qb  = wpt + (size_t)CDIM * CDIM;      // [BH][N][64] (q pre-scaled)
    short* kb  = qb  + SZ;                       // [BH][N][64]
    short* vt  = kb  + SZ;                       // [BH][64][N]
    short* ao  = vt  + SZ;                       // [4096][768]
    float* opart = (float*)(ao + SZ);            // [1536][64q][64d] fp32
    float* lpart = opart + (size_t)NBLK_ATTN * 4096;  // [1536][64]

    dim3 blk(256);
    prep_kernel<<<dim3(5376), blk, 0, stream>>>(x, w_qkv, w_proj, xb, wqt, wpt);
    gemm_qkv<<<dim3(QKV_COLS/128, NTOK/128), blk, 0, stream>>>(wqt, xb, qb, kb, vt);
    attn_kernel<<<dim3(NBLK_ATTN), blk, 0, stream>>>(qb, kb, vt, mask, opart, lpart);
    attn_reduce<<<dim3(NBLK_RED), blk, 0, stream>>>(opart, lpart, ao);
    gemm_proj<<<dim3(CDIM/128, NTOK/128), blk, 0, stream>>>(wpt, ao, b_proj, out);
}

// Round 11
// 184.066 us; speedup vs baseline: 1.0096x; 1.0096x over previous
//
#include <hip/hip_runtime.h>
#include <cstdint>

#define NB 2
#define NSEQ 2048
#define CDIM 768
#define NH 12
#define HD 64
#define NTOK (NB*NSEQ)        // 4096
#define QKV_COLS (3*CDIM)     // 2304
#define NBLK ((NSEQ/64)*NH*NB) // 768 attn blocks

typedef short bf16x8 __attribute__((ext_vector_type(8)));
typedef short bf16x4 __attribute__((ext_vector_type(4)));
typedef float f32x4  __attribute__((ext_vector_type(4)));
typedef short short4v __attribute__((ext_vector_type(4)));
typedef unsigned int uint4v __attribute__((ext_vector_type(4)));

#define MFMA16(a,b,c) __builtin_amdgcn_mfma_f32_16x16x32_bf16(a,b,c,0,0,0)

__device__ __forceinline__ short f2b(float f) {
    uint32_t u = __builtin_bit_cast(uint32_t, f);
    u += 0x7fffu + ((u >> 16) & 1u);
    return (short)(u >> 16);
}
__device__ __forceinline__ unsigned pack2(float a, float b) {
    unsigned ua = __builtin_bit_cast(unsigned, a) + 0x7fffu;
    unsigned ub = __builtin_bit_cast(unsigned, b) + 0x7fffu;
    return __builtin_amdgcn_perm(ub, ua, 0x07060302u);
}
__device__ __forceinline__ void gll16(const short* g, short* l) {
    __builtin_amdgcn_global_load_lds(
        (const __attribute__((address_space(1))) unsigned int*)g,
        (__attribute__((address_space(3))) unsigned int*)l, 16, 0, 0);
}

// ---------------------------------------------------------------------------
// Merged prep: x fp32->bf16 (blocks 0..3071), w_qkv T (..4799), w_proj T (..5375)
// ---------------------------------------------------------------------------
__global__ __launch_bounds__(256) void prep_kernel(
    const float* __restrict__ x, const float* __restrict__ w_qkv,
    const float* __restrict__ w_proj,
    short* __restrict__ xb, short* __restrict__ wqt, short* __restrict__ wpt)
{
    __shared__ float tile[32][33];
    const int bid = blockIdx.x, t = threadIdx.x;
    if (bid < 3072) {
        int i = bid * 256 + t;
        float4 v = ((const float4*)x)[i];
        short4v o = { f2b(v.x), f2b(v.y), f2b(v.z), f2b(v.w) };
        ((short4v*)xb)[i] = o;
        return;
    }
    const float* w; short* wt; int K, NC, n0, k0;
    if (bid < 3072 + 1728) {
        int r = bid - 3072;
        w = w_qkv; wt = wqt; K = CDIM; NC = QKV_COLS;
        n0 = (r % 72) * 32; k0 = (r / 72) * 32;
    } else {
        int r = bid - 4800;
        w = w_proj; wt = wpt; K = CDIM; NC = CDIM;
        n0 = (r % 24) * 32; k0 = (r / 24) * 32;
    }
    #pragma unroll
    for (int i = 0; i < 4; ++i) {
        int idx = t + i * 256; int r = idx >> 5, c = idx & 31;
        tile[r][c] = w[(size_t)(k0 + r) * NC + n0 + c];
    }
    __syncthreads();
    #pragma unroll
    for (int i = 0; i < 4; ++i) {
        int idx = t + i * 256; int r = idx >> 5, c = idx & 31;
        wt[(size_t)(n0 + r) * K + k0 + c] = f2b(tile[c][r]);
    }
}

// ---------------------------------------------------------------------------
// GEMM 64x128 tile (cols x tokens): grid 2x bigger than 128x128 -> 4.5+
// blocks/CU. Per wave: 32 cols x 64 toks = acc[2][4], 8 MFMA per BK=32.
// LDS: A dbuf 2x4KB + B dbuf 2x8KB = 24KB. 1 barrier per stage.
// ---------------------------------------------------------------------------
#define GSTAGE(K0, BUF) do {                                                     \
    gll16(ag + (K0), As + (BUF)*4096 + wid*512);                                 \
    gll16(bg0 + (K0), Bs + (BUF)*8192 + wid*1024);                               \
    gll16(bg1 + (K0), Bs + (BUF)*8192 + wid*1024 + 512);                         \
} while (0)

#define GCOMP(BUF) do {                                                          \
    const short* A_ = As + (BUF)*4096;                                           \
    const short* B_ = Bs + (BUF)*8192;                                           \
    bf16x8 af_[2], bf_[4];                                                       \
    _Pragma("unroll")                                                            \
    for (int i = 0; i < 2; ++i)                                                  \
        af_[i] = *(const bf16x8*)&A_[(wA*32 + i*16 + l16) * 32 + quad*8];        \
    _Pragma("unroll")                                                            \
    for (int j = 0; j < 4; ++j)                                                  \
        bf_[j] = *(const bf16x8*)&B_[(wB*64 + j*16 + l16) * 32 + quad*8];        \
    _Pragma("unroll")                                                            \
    for (int i = 0; i < 2; ++i)                                                  \
        _Pragma("unroll")                                                        \
        for (int j = 0; j < 4; ++j)                                              \
            acc[i][j] = MFMA16(af_[i], bf_[j], acc[i][j]);                       \
} while (0)

#define GEMM_LOOP() do {                                                         \
    GSTAGE(0, 0); __syncthreads();                                               \
    for (int k0 = 0; k0 < CDIM; k0 += 64) {                                      \
        GSTAGE(k0 + 32, 1);                                                      \
        GCOMP(0);                                                                \
        __syncthreads();                                                         \
        GSTAGE((k0 + 64 < CDIM) ? k0 + 64 : 0, 0);                               \
        GCOMP(1);                                                                \
        __syncthreads();                                                         \
    }                                                                            \
} while (0)

__global__ __launch_bounds__(256) void gemm_qkv(
    const short* __restrict__ A /*wqt[2304][768]*/,
    const short* __restrict__ B /*xb [4096][768]*/,
    short* __restrict__ qb, short* __restrict__ kb, short* __restrict__ vt)
{
    __shared__ __align__(16) short As[8192];    // 2 x 64x32
    __shared__ __align__(16) short Bs[16384];   // 2 x 128x32
    const int t = threadIdx.x;
    const int lane = t & 63, wid = t >> 6;
    const int quad = lane >> 4, l16 = lane & 15;
    const int wA = wid >> 1, wB = wid & 1;
    const int n0 = blockIdx.x * 64;    // col base (one head)
    const int m0 = blockIdx.y * 128;   // token base

    const short* ag  = A + (size_t)(n0 + wid*16 + (lane >> 2)) * CDIM + (lane & 3)*8;
    const short* bg0 = B + (size_t)(m0 + wid*32 + (lane >> 2)) * CDIM + (lane & 3)*8;
    const short* bg1 = bg0 + (size_t)16 * CDIM;

    f32x4 acc[2][4] = {};
    GEMM_LOOP();

    const int s = n0 / CDIM;                    // block-uniform
    const int h = (n0 - s * CDIM) >> 6;
    const int b = m0 >> 11;
    const size_t bh = (size_t)(b * NH + h);
    const float qsc = (s == 0) ? 0.125f : 1.0f;
    #pragma unroll
    for (int i = 0; i < 2; ++i) {
        const int d0 = wA*32 + i*16 + quad*4;
        #pragma unroll
        for (int j = 0; j < 4; ++j) {
            int tok = (m0 & (NSEQ - 1)) + wB*64 + j*16 + l16;
            if (s < 2) {
                short* dst = (s == 0 ? qb : kb) + (bh * NSEQ + tok) * HD + d0;
                short4v o = { f2b(acc[i][j][0]*qsc), f2b(acc[i][j][1]*qsc),
                              f2b(acc[i][j][2]*qsc), f2b(acc[i][j][3]*qsc) };
                *(short4v*)dst = o;
            } else {
                short* dst = vt + (bh * HD + d0) * NSEQ + tok;
                #pragma unroll
                for (int r = 0; r < 4; ++r)
                    dst[(size_t)r * NSEQ] = f2b(acc[i][j][r]);
            }
        }
    }
}

// ---------------------------------------------------------------------------
// Flash attention v8 (verbatim round 8, best measured 59.0 us): cooperative
// swizzled K+V staging, double-buffered (2 x 32 KB), 1 barrier per 128-key
// tile; P in registers; direct ao output.
// ---------------------------------------------------------------------------
#define STAGE(KT, BUF) do {                                                      \
    short* kb_ = (BUF);                                                          \
    short* vb_ = (BUF) + 8192;                                                   \
    _Pragma("unroll")                                                            \
    for (int j = 0; j < 4; ++j) {                                                \
        gll16(kp + (size_t)((KT) + rK[j]) * HD + cK[j]*8,                        \
              kb_ + wid*2048 + j*512);                                           \
        gll16(vp + (size_t)dV[j] * NSEQ + (KT) + cV[j]*8,                        \
              vb_ + wid*2048 + j*512);                                           \
    }                                                                            \
} while (0)

#define BODY(KT, BUF) do {                                                       \
    const short* KsB_ = (BUF);                                                   \
    const short* VsB_ = (BUF) + 8192;                                            \
    int4 mi0_ = *(const int4*)(mp + (KT) + kbase);                               \
    int4 mi1_ = *(const int4*)(mp + (KT) + 64 + kbase);                          \
    bf16x8 kf00_ = *(const bf16x8*)&KsB_[krow + kc0];                            \
    bf16x8 kf01_ = *(const bf16x8*)&KsB_[krow + kc1];                            \
    bf16x8 kf10_ = *(const bf16x8*)&KsB_[4096 + krow + kc0];                     \
    bf16x8 kf11_ = *(const bf16x8*)&KsB_[4096 + krow + kc1];                     \
    f32x4 s0_[4] = {}, s1_[4] = {};                                              \
    _Pragma("unroll")                                                            \
    for (int jt = 0; jt < 4; ++jt) {                                             \
        s0_[jt] = MFMA16(kf00_, qf[jt][0], s0_[jt]);                             \
        s0_[jt] = MFMA16(kf01_, qf[jt][1], s0_[jt]);                             \
        s1_[jt] = MFMA16(kf10_, qf[jt][0], s1_[jt]);                             \
        s1_[jt] = MFMA16(kf11_, qf[jt][1], s1_[jt]);                             \
    }                                                                            \
    float4 m0_ = {(float)mi0_.x, (float)mi0_.y, (float)mi0_.z, (float)mi0_.w};   \
    float4 m1_ = {(float)mi1_.x, (float)mi1_.y, (float)mi1_.z, (float)mi1_.w};   \
    bf16x8 pb_[4];                                                               \
    _Pragma("unroll")                                                            \
    for (int jt = 0; jt < 4; ++jt) {                                             \
        float e0 = __expf(s0_[jt][0]) * m0_.x;                                   \
        float e1 = __expf(s0_[jt][1]) * m0_.y;                                   \
        float e2 = __expf(s0_[jt][2]) * m0_.z;                                   \
        float e3 = __expf(s0_[jt][3]) * m0_.w;                                   \
        float f0 = __expf(s1_[jt][0]) * m1_.x;                                   \
        float f1 = __expf(s1_[jt][1]) * m1_.y;                                   \
        float f2 = __expf(s1_[jt][2]) * m1_.z;                                   \
        float f3 = __expf(s1_[jt][3]) * m1_.w;                                   \
        l[jt] += ((e0 + e1) + (e2 + e3)) + ((f0 + f1) + (f2 + f3));              \
        uint4v pk_ = { pack2(e0, e1), pack2(e2, e3),                             \
                       pack2(f0, f1), pack2(f2, f3) };                           \
        pb_[jt] = __builtin_bit_cast(bf16x8, pk_);                               \
    }                                                                            \
    _Pragma("unroll")                                                            \
    for (int it = 0; it < 4; ++it) {                                             \
        const int vrow_ = (it*16 + l16) * 128;                                   \
        bf16x4 lo_ = *(const bf16x4*)&VsB_[vrow_ + vposl + vsub];                \
        bf16x4 hi_ = *(const bf16x4*)&VsB_[vrow_ + vposh + vsub];                \
        bf16x8 vf_ = __builtin_shufflevector(lo_, hi_, 0,1,2,3,4,5,6,7);         \
        _Pragma("unroll")                                                        \
        for (int jt = 0; jt < 4; ++jt)                                           \
            o_acc[it][jt] = MFMA16(vf_, pb_[jt], o_acc[it][jt]);                 \
    }                                                                            \
} while (0)

__global__ __launch_bounds__(256, 2) void attn_kernel(
    const short* __restrict__ qb, const short* __restrict__ kb,
    const short* __restrict__ vt, const int* __restrict__ mask,
    short* __restrict__ ao)
{
    __shared__ __align__(16) short KV[2][16384];   // [buf][K 16KB | V 16KB]
    float (*Ob)[68] = (float(*)[68])KV;            // epilogue alias
    float (*lsum)[64] = (float(*)[64])((char*)KV + 17408);

    const int t = threadIdx.x;
    const int lane = t & 63, wid = t >> 6;
    const int quad = lane >> 4, l16 = lane & 15;
    // XCD swizzle: XCD = id%8 owns bh in {xcd, xcd+8, xcd+16}
    const int id = blockIdx.x;
    const int idx = id >> 3;
    const int bh = (id & 7) + ((idx % 3) << 3);
    const int q0 = (idx / 3) << 6;
    const int b = bh / NH, h = bh - b * NH;
    const size_t hoff = (size_t)bh * NSEQ * HD;
    const short* qp = qb + hoff;     // [N][64]  (q pre-scaled by 0.125)
    const short* kp = kb + hoff;     // [N][64]
    const short* vp = vt + hoff;     // [64][N]
    const int* mp = mask + b * NSEQ;
    const int kbase = wid * 16 + quad * 4;

    int rK[4], cK[4], dV[4], cV[4];
    #pragma unroll
    for (int j = 0; j < 4; ++j) {
        int o = wid * 4096 + j * 1024 + lane * 16;
        rK[j] = o >> 7;
        cK[j] = ((o >> 4) & 7) ^ (rK[j] & 7);
        dV[j] = o >> 8;
        cV[j] = ((o >> 4) & 15) ^ (dV[j] & 15);
    }
    const int r7 = l16 & 7;
    const int krow = (wid * 16 + l16) * 64;
    const int kc0 = ((quad     ^ r7) << 3);
    const int kc1 = (((quad+4) ^ r7) << 3);
    const int vposl = ((wid*2 + (quad >> 1)) ^ l16) << 3;
    const int vposh = (((8 + wid*2 + (quad >> 1)) ^ l16) << 3);
    const int vsub = (quad & 1) * 4;

    bf16x8 qf[4][2];
    #pragma unroll
    for (int jt = 0; jt < 4; ++jt) {
        const short* qr = qp + (size_t)(q0 + jt*16 + l16) * HD + quad*8;
        qf[jt][0] = *(const bf16x8*)qr;
        qf[jt][1] = *(const bf16x8*)(qr + 32);
    }

    f32x4 o_acc[4][4] = {};
    float l[4] = {0.f, 0.f, 0.f, 0.f};

    STAGE(0, KV[0]);
    __syncthreads();

    for (int kt = 0; kt < NSEQ; kt += 256) {
        STAGE(kt + 128, KV[1]);
        BODY(kt, KV[0]);
        __syncthreads();
        const int nx = (kt + 256) & (NSEQ - 1);
        STAGE(nx, KV[0]);
        BODY(kt + 128, KV[1]);
        __syncthreads();
    }

    #pragma unroll
    for (int jt = 0; jt < 4; ++jt) {
        l[jt] += __shfl_xor(l[jt], 16);
        l[jt] += __shfl_xor(l[jt], 32);
        if (quad == 0) lsum[wid][jt*16 + l16] = l[jt];
    }
    for (int w = 0; w < 4; ++w) {
        __syncthreads();
        if (wid == w) {
            #pragma unroll
            for (int it = 0; it < 4; ++it)
                #pragma unroll
                for (int jt = 0; jt < 4; ++jt)
                    #pragma unroll
                    for (int r = 0; r < 4; ++r) {
                        if (w == 0)
                            Ob[it*16 + quad*4 + r][jt*16 + l16] = o_acc[it][jt][r];
                        else
                            Ob[it*16 + quad*4 + r][jt*16 + l16] += o_acc[it][jt][r];
                    }
        }
    }
    __syncthreads();

    {
        const int ql = t >> 2, dc = (t & 3) * 16;
        float inv = 1.0f / (((lsum[0][ql] + lsum[1][ql]) +
                             (lsum[2][ql] + lsum[3][ql])));
        bf16x8 o8a, o8b;
        #pragma unroll
        for (int d = 0; d < 8; ++d) o8a[d] = f2b(Ob[dc + d][ql] * inv);
        #pragma unroll
        for (int d = 0; d < 8; ++d) o8b[d] = f2b(Ob[dc + 8 + d][ql] * inv);
        int tok = b * NSEQ + q0 + ql;
        short* dst = ao + (size_t)tok * CDIM + h * HD + dc;
        *(bf16x8*)dst = o8a;
        *(bf16x8*)(dst + 8) = o8b;
    }
}

// ---------------------------------------------------------------------------
// GEMM2: 64x128 tile, grid 384. out = ao @ w_proj + bias (fp32).
// ---------------------------------------------------------------------------
__global__ __launch_bounds__(256) void gemm_proj(
    const short* __restrict__ A /*wpt[768][768]*/,
    const short* __restrict__ B /*ao [4096][768]*/,
    const float* __restrict__ bias, float* __restrict__ out)
{
    __shared__ __align__(16) short As[8192];
    __shared__ __align__(16) short Bs[16384];
    const int t = threadIdx.x;
    const int lane = t & 63, wid = t >> 6;
    const int quad = lane >> 4, l16 = lane & 15;
    const int wA = wid >> 1, wB = wid & 1;
    const int n0 = blockIdx.x * 64;
    const int m0 = blockIdx.y * 128;

    const short* ag  = A + (size_t)(n0 + wid*16 + (lane >> 2)) * CDIM + (lane & 3)*8;
    const short* bg0 = B + (size_t)(m0 + wid*32 + (lane >> 2)) * CDIM + (lane & 3)*8;
    const short* bg1 = bg0 + (size_t)16 * CDIM;

    f32x4 acc[2][4] = {};
    GEMM_LOOP();

    #pragma unroll
    for (int i = 0; i < 2; ++i) {
        int col0 = n0 + wA*32 + i*16 + quad*4;
        float4 bias4 = *(const float4*)&bias[col0];
        #pragma unroll
        for (int j = 0; j < 4; ++j) {
            int tok = m0 + wB*64 + j*16 + l16;
            float4 o = { acc[i][j][0] + bias4.x, acc[i][j][1] + bias4.y,
                         acc[i][j][2] + bias4.z, acc[i][j][3] + bias4.w };
            *(float4*)(out + (size_t)tok * CDIM + col0) = o;
        }
    }
}

extern "C" void kernel_launch(void* const* d_in, const int* in_sizes, int n_in,
                              void* d_out, int out_size, void* d_ws, size_t ws_size,
                              hipStream_t stream)
{
    const float* x      = (const float*)d_in[0];
    const int*   mask   = (const int*)d_in[1];
    const float* w_qkv  = (const float*)d_in[2];
    const float* w_proj = (const float*)d_in[3];
    const float* b_proj = (const float*)d_in[4];
    float* out = (float*)d_out;

    const size_t SZ = (size_t)NTOK * CDIM;       // 3,145,728
    short* xb  = (short*)d_ws;                   // [4096][768]
    short* wqt = xb  + SZ;                       // [2304][768]
    short* wpt = wqt + (size_t)QKV_COLS * CDIM;  // [768][768]
    short* qb  = wpt + (size_t)CDIM * CDIM;      // [BH][N][64] (q pre-scaled)
    short* kb  = qb  + SZ;                       // [BH][N][64]
    short* vt  = kb  + SZ;                       // [BH][64][N]
    short* ao  = vt  + SZ;                       // [4096][768]

    dim3 blk(256);
    prep_kernel<<<dim3(5376), blk, 0, stream>>>(x, w_qkv, w_proj, xb, wqt, wpt);
    gemm_qkv<<<dim3(QKV_COLS/64, NTOK/128), blk, 0, stream>>>(wqt, xb, qb, kb, vt);
    attn_kernel<<<dim3(NBLK), blk, 0, stream>>>(qb, kb, vt, mask, ao);
    gemm_proj<<<dim3(CDIM/64, NTOK/128), blk, 0, stream>>>(wpt, ao, b_proj, out);
}